// Round 1
// baseline (2962.612 us; speedup 1.0000x reference)
//
#include <hip/hip_runtime.h>
#include <cstdint>
#include <cstddef>

typedef short short8_t __attribute__((ext_vector_type(8)));
typedef float float4_t __attribute__((ext_vector_type(4)));

#define F_ENC   64
#define HOR     32
#define NSTEPS  95   // 64 encoder steps + 31 AR steps; preds emitted at t=63..94

// Fragment-packed weights in device globals (rebuilt from d_in every call by prep_kernel).
// g_W frag id f = ((g*4 + w)*4 + s)*12 + kt, elem off = f*512 + lane*8
__device__ __align__(16) unsigned short g_W[1024 * 384];
__device__ float g_bias[1024];
// g_Wlin frag id f = (w*2 + s)*8 + kt
__device__ __align__(16) unsigned short g_Wlin[128 * 256];
__device__ float g_blin[128];

__device__ __forceinline__ unsigned short f2bf_rn(float f) {
    union { float f; unsigned int u; } v; v.f = f;
    unsigned int u = v.u;
    return (unsigned short)((u + 0x7FFFu + ((u >> 16) & 1u)) >> 16);
}
__device__ __forceinline__ float sigm(float x) { return 1.0f / (1.0f + __expf(-x)); }
// overflow-safe tanh: 2*sigmoid(2x)-1 (inf handled gracefully by rcp)
__device__ __forceinline__ float tanh_fast(float x) { return 2.0f / (1.0f + __expf(-2.0f * x)) - 1.0f; }

__global__ void prep_kernel(const float* __restrict__ w_ih, const float* __restrict__ w_hh,
                            const float* __restrict__ b_ih, const float* __restrict__ b_hh,
                            const float* __restrict__ w_lin, const float* __restrict__ b_lin) {
    int idx = blockIdx.x * blockDim.x + threadIdx.x;
    int stride = gridDim.x * blockDim.x;
    // pack [w_ih | w_hh] -> g_W (bf16, fragment-major)
    for (int i = idx; i < 49152; i += stride) {   // 768 frags * 64 lanes
        int f = i >> 6;
        int l = i & 63;
        int kt = f % 12;
        int rest = f / 12;          // (g*4 + w)*4 + s
        int s = rest & 3;
        int gw = rest >> 2;
        int wvv = gw & 3;
        int g = gw >> 2;
        int n = g * 256 + wvv * 64 + s * 16 + (l & 15);
        int k0 = kt * 32 + (l >> 4) * 8;
        unsigned short* dst = g_W + f * 512 + l * 8;
#pragma unroll
        for (int j = 0; j < 8; ++j) {
            int k = k0 + j;
            float v = (k < 128) ? w_ih[n * 128 + k] : w_hh[n * 256 + (k - 128)];
            dst[j] = f2bf_rn(v);
        }
    }
    // pack w_lin -> g_Wlin
    for (int i = idx; i < 4096; i += stride) {    // 64 frags * 64 lanes
        int f = i >> 6;
        int l = i & 63;
        int kt = f & 7;
        int wss = f >> 3;           // w*2 + s
        int s = wss & 1;
        int wvv = wss >> 1;
        int n = wvv * 32 + s * 16 + (l & 15);
        int k0 = kt * 32 + (l >> 4) * 8;
        unsigned short* dst = g_Wlin + f * 512 + l * 8;
#pragma unroll
        for (int j = 0; j < 8; ++j)
            dst[j] = f2bf_rn(w_lin[n * 256 + k0 + j]);
    }
    for (int i = idx; i < 1024; i += stride) g_bias[i] = b_ih[i] + b_hh[i];
    for (int i = idx; i < 128; i += stride) g_blin[i] = b_lin[i];
}

// Persistent LSTM: each block owns 16 batch rows for all 95 steps. 4 waves:
// wave w computes gate columns {g*256 + w*64 .. +63} for g in {i,f,g,o},
// so c/h updates are lane-local. h round-trips via swizzled LDS each step.
__global__ void __launch_bounds__(256) lstm_persist(const float* __restrict__ inp,
                                                    float* __restrict__ out) {
    __shared__ __align__(16) unsigned short h_sh[16 * 256];  // bf16, XOR-swizzled
    __shared__ __align__(16) unsigned short p_sh[16 * 128];  // bf16, XOR-swizzled

    const int tid = threadIdx.x;
    const int wv  = tid >> 6;    // wave 0..3
    const int l   = tid & 63;
    const int l15 = l & 15;
    const int lg  = l >> 4;      // 0..3
    const int b0  = blockIdx.x << 4;

    float bias_r[4][4];
#pragma unroll
    for (int g = 0; g < 4; ++g)
#pragma unroll
        for (int s = 0; s < 4; ++s)
            bias_r[g][s] = g_bias[g * 256 + wv * 64 + s * 16 + l15];
    float blin_r[2];
#pragma unroll
    for (int s = 0; s < 2; ++s)
        blin_r[s] = g_blin[wv * 32 + s * 16 + l15];

    const unsigned short* wbase  = g_W    + wv * 24576 + l * 8;
    const unsigned short* wlbase = g_Wlin + wv * 8192  + l * 8;
    const float* inp_lane = inp + (size_t)(b0 + l15) * (F_ENC * 128) + lg * 8;

    short8_t ha[8];
    short8_t zz = {0, 0, 0, 0, 0, 0, 0, 0};
#pragma unroll
    for (int i = 0; i < 8; ++i) ha[i] = zz;
    short8_t xa[4];
    float c_st[4][4];
#pragma unroll
    for (int s = 0; s < 4; ++s)
#pragma unroll
        for (int r = 0; r < 4; ++r) c_st[s][r] = 0.0f;

    for (int t = 0; t < NSTEPS; ++t) {
        // ---- A: x fragments (global f32 for encoder, p_sh for AR) ----
        if (t < F_ENC) {
            const float* xp = inp_lane + t * 128;
#pragma unroll
            for (int kt = 0; kt < 4; ++kt) {
                float4_t x0 = *(const float4_t*)(xp + kt * 32);
                float4_t x1 = *(const float4_t*)(xp + kt * 32 + 4);
                short8_t vv;
                vv[0] = (short)f2bf_rn(x0[0]); vv[1] = (short)f2bf_rn(x0[1]);
                vv[2] = (short)f2bf_rn(x0[2]); vv[3] = (short)f2bf_rn(x0[3]);
                vv[4] = (short)f2bf_rn(x1[0]); vv[5] = (short)f2bf_rn(x1[1]);
                vv[6] = (short)f2bf_rn(x1[2]); vv[7] = (short)f2bf_rn(x1[3]);
                xa[kt] = vv;
            }
        } else {
#pragma unroll
            for (int kt = 0; kt < 4; ++kt) {
                int off = (l15 * 256 + kt * 64 + lg * 16) ^ ((l15 & 7) << 4);
                xa[kt] = *(const short8_t*)((const char*)p_sh + off);
            }
        }

        // ---- B: gates GEMM, bias folded into acc init ----
        float4_t acc[4][4];
#pragma unroll
        for (int g = 0; g < 4; ++g)
#pragma unroll
            for (int s = 0; s < 4; ++s) {
                float b = bias_r[g][s];
                acc[g][s] = (float4_t){b, b, b, b};
            }
#pragma unroll
        for (int kt = 0; kt < 12; ++kt) {
            short8_t a = (kt < 4) ? xa[kt] : ha[kt - 4];
#pragma unroll
            for (int g = 0; g < 4; ++g)
#pragma unroll
                for (int s = 0; s < 4; ++s) {
                    const short8_t wf = *(const short8_t*)(wbase + g * 98304 + s * 6144 + kt * 512);
                    acc[g][s] = __builtin_amdgcn_mfma_f32_16x16x32_bf16(a, wf, acc[g][s], 0, 0, 0);
                }
        }
        __syncthreads();   // all waves done reading h_sh/p_sh of previous step

        // ---- C/D: pointwise gates, c update, write h (bf16, swizzled) ----
#pragma unroll
        for (int s = 0; s < 4; ++s)
#pragma unroll
            for (int r = 0; r < 4; ++r) {
                float ip = acc[0][s][r];
                float fp = acc[1][s][r];
                float gp = acc[2][s][r];
                float op = acc[3][s][r];
                float cn = sigm(fp) * c_st[s][r] + sigm(ip) * tanh_fast(gp);
                c_st[s][r] = cn;
                float hv = sigm(op) * tanh_fast(cn);
                int m = lg * 4 + r;
                int col = wv * 64 + s * 16 + l15;
                int off = (m * 512 + col * 2) ^ ((m & 7) << 4);
                *(unsigned short*)((char*)h_sh + off) = f2bf_rn(hv);
            }
        __syncthreads();   // h_sh complete

        // ---- E: reload h fragments (feeds next step's GEMM and the pred GEMM) ----
#pragma unroll
        for (int kt = 0; kt < 8; ++kt) {
            int off = (l15 * 512 + kt * 64 + lg * 16) ^ ((l15 & 7) << 4);
            ha[kt] = *(const short8_t*)((const char*)h_sh + off);
        }

        if (t >= F_ENC - 1) {
            int ko = t - (F_ENC - 1);   // 0..31
            float4_t pacc[2];
#pragma unroll
            for (int s = 0; s < 2; ++s) {
                float b = blin_r[s];
                pacc[s] = (float4_t){b, b, b, b};
            }
#pragma unroll
            for (int kt = 0; kt < 8; ++kt)
#pragma unroll
                for (int s = 0; s < 2; ++s) {
                    const short8_t wf = *(const short8_t*)(wlbase + s * 4096 + kt * 512);
                    pacc[s] = __builtin_amdgcn_mfma_f32_16x16x32_bf16(ha[kt], wf, pacc[s], 0, 0, 0);
                }
#pragma unroll
            for (int s = 0; s < 2; ++s)
#pragma unroll
                for (int r = 0; r < 4; ++r) {
                    float pv = pacc[s][r];
                    int m = lg * 4 + r;
                    int col = wv * 32 + s * 16 + l15;
                    out[(size_t)(b0 + m) * (HOR * 128) + (size_t)ko * 128 + col] = pv;
                    int off2 = (m * 256 + col * 2) ^ ((m & 7) << 4);
                    *(unsigned short*)((char*)p_sh + off2) = f2bf_rn(pv);
                }
            __syncthreads();   // p_sh ready for next step's A-phase
        }
    }
}

extern "C" void kernel_launch(void* const* d_in, const int* in_sizes, int n_in,
                              void* d_out, int out_size, void* d_ws, size_t ws_size,
                              hipStream_t stream) {
    const float* inp   = (const float*)d_in[0];
    const float* w_ih  = (const float*)d_in[1];
    const float* w_hh  = (const float*)d_in[2];
    const float* b_ih  = (const float*)d_in[3];
    const float* b_hh  = (const float*)d_in[4];
    const float* w_lin = (const float*)d_in[5];
    const float* b_lin = (const float*)d_in[6];
    (void)in_sizes; (void)n_in; (void)d_ws; (void)ws_size; (void)out_size;

    prep_kernel<<<128, 256, 0, stream>>>(w_ih, w_hh, b_ih, b_hh, w_lin, b_lin);
    lstm_persist<<<128, 256, 0, stream>>>(inp, (float*)d_out);
}

// Round 2
// 2359.198 us; speedup vs baseline: 1.2558x; 1.2558x over previous
//
#include <hip/hip_runtime.h>
#include <cstdint>
#include <cstddef>

typedef short short8_t __attribute__((ext_vector_type(8)));
typedef float float4_t __attribute__((ext_vector_type(4)));

#define NB_C 8     // column-split blocks per row-group
#define NRG  32    // row-groups (64 batch rows each)

// Fragment-packed weights (rebuilt from d_in every call by prep_kernel).
// g_W frag id f = ((g*4 + w)*4 + s)*12 + kt, elem off = f*512 + lane*8
__device__ __align__(16) unsigned short g_W[1024 * 384];
__device__ float g_bias[1024];
__device__ __align__(16) unsigned short g_Wlin[128 * 256];
__device__ float g_blin[128];
// h exchange: [rg][parity][frag rt*8+kt][lane*8], A-fragment packed
__device__ __align__(16) unsigned short g_hbuf[NRG][2][32][512];
__device__ int g_arrive[NRG * 96];

__device__ __forceinline__ unsigned short f2bf_rn(float f) {
    union { float f; unsigned int u; } v; v.f = f;
    unsigned int u = v.u;
    return (unsigned short)((u + 0x7FFFu + ((u >> 16) & 1u)) >> 16);
}
__device__ __forceinline__ float sigm(float x) { return 1.0f / (1.0f + __expf(-x)); }
__device__ __forceinline__ float tanh_fast(float x) { return 2.0f / (1.0f + __expf(-2.0f * x)) - 1.0f; }

__global__ void prep_kernel(const float* __restrict__ w_ih, const float* __restrict__ w_hh,
                            const float* __restrict__ b_ih, const float* __restrict__ b_hh,
                            const float* __restrict__ w_lin, const float* __restrict__ b_lin) {
    int idx = blockIdx.x * blockDim.x + threadIdx.x;
    int stride = gridDim.x * blockDim.x;
    for (int i = idx; i < 49152; i += stride) {   // 768 frags * 64 lanes
        int f = i >> 6;
        int l = i & 63;
        int kt = f % 12;
        int rest = f / 12;          // (g*4 + w)*4 + s
        int s = rest & 3;
        int gw = rest >> 2;
        int wvv = gw & 3;
        int g = gw >> 2;
        int n = g * 256 + wvv * 64 + s * 16 + (l & 15);
        int k0 = kt * 32 + (l >> 4) * 8;
        unsigned short* dst = g_W + f * 512 + l * 8;
#pragma unroll
        for (int j = 0; j < 8; ++j) {
            int k = k0 + j;
            float v = (k < 128) ? w_ih[n * 128 + k] : w_hh[n * 256 + (k - 128)];
            dst[j] = f2bf_rn(v);
        }
    }
    for (int i = idx; i < 4096; i += stride) {    // 64 frags * 64 lanes
        int f = i >> 6;
        int l = i & 63;
        int kt = f & 7;
        int wss = f >> 3;           // w*2 + s
        int s = wss & 1;
        int wvv = wss >> 1;
        int n = wvv * 32 + s * 16 + (l & 15);
        int k0 = kt * 32 + (l >> 4) * 8;
        unsigned short* dst = g_Wlin + f * 512 + l * 8;
#pragma unroll
        for (int j = 0; j < 8; ++j)
            dst[j] = f2bf_rn(w_lin[n * 256 + k0 + j]);
    }
    for (int i = idx; i < 1024; i += stride) g_bias[i] = b_ih[i] + b_hh[i];
    for (int i = idx; i < 128; i += stride) g_blin[i] = b_lin[i];
    for (int i = idx; i < NRG * 96; i += stride) g_arrive[i] = 0;
}

// 256 blocks = 32 row-groups x 8 col-blocks. Block (rg,c): 64 rows, gate dims
// [c*32, c*32+32) of each of the 4 gates (128 gate cols). Gate weights LDS-
// resident (96 KiB). h exchanged per step via g_hbuf + arrival counters.
__global__ void __launch_bounds__(256, 1) lstm_persist(const float* __restrict__ inp,
                                                       float* __restrict__ out) {
    __shared__ __align__(16) unsigned short gw[96 * 512];   // 96 KiB gate-weight slice
    __shared__ __align__(16) unsigned short pst[4][2048];   // 4 KiB/wave pred->xa staging

    const int tid = threadIdx.x;
    const int wv  = tid >> 6;
    const int l   = tid & 63;
    const int l15 = l & 15;
    const int lg  = l >> 4;
    const int bid = blockIdx.x;
    const int c   = bid >> 5;   // col-block 0..7
    const int rg  = bid & 31;   // row-group 0..31 (co-locates a rg's 8 blocks on one XCD)

    // ---- load gate-weight slice into LDS ----
    for (int i = tid; i < 96 * 64; i += 256) {
        int lf = i >> 6, ch = i & 63;
        int kt = lf % 12;
        int gs = lf / 12;             // g*2 + s2
        int s2 = gs & 1, g = gs >> 1;
        int gf = ((g * 4 + (c >> 1)) * 4 + 2 * (c & 1) + s2) * 12 + kt;
        *(uint4*)&gw[lf * 512 + ch * 8] = *(const uint4*)&g_W[gf * 512 + ch * 8];
    }

    float bias_r[4][2];
#pragma unroll
    for (int g = 0; g < 4; ++g)
#pragma unroll
        for (int s2 = 0; s2 < 2; ++s2)
            bias_r[g][s2] = g_bias[g * 256 + c * 32 + s2 * 16 + l15];
    float blin_r[8];
#pragma unroll
    for (int cf = 0; cf < 8; ++cf) blin_r[cf] = g_blin[cf * 16 + l15];

    // wlin kt 0..3 persistent in VGPRs (kt 4..7 streamed per AR step)
    short8_t wl[8][4];
#pragma unroll
    for (int cf = 0; cf < 8; ++cf)
#pragma unroll
        for (int kk = 0; kk < 4; ++kk)
            wl[cf][kk] = *(const short8_t*)&g_Wlin[(cf * 8 + kk) * 512 + l * 8];

    __syncthreads();

    short8_t ha[8];
    short8_t zz = {0, 0, 0, 0, 0, 0, 0, 0};
#pragma unroll
    for (int i = 0; i < 8; ++i) ha[i] = zz;
    short8_t xa[4];
#pragma unroll
    for (int i = 0; i < 4; ++i) xa[i] = zz;
    float c_st[2][4];
#pragma unroll
    for (int s2 = 0; s2 < 2; ++s2)
#pragma unroll
        for (int r = 0; r < 4; ++r) c_st[s2][r] = 0.0f;

    const float* xrow = inp + (size_t)(rg * 64 + wv * 16 + l15) * 8192 + lg * 8;
    float4_t xf[8];
#pragma unroll
    for (int kt = 0; kt < 4; ++kt) {            // prefetch x(0)
        xf[2 * kt]     = *(const float4_t*)(xrow + kt * 32);
        xf[2 * kt + 1] = *(const float4_t*)(xrow + kt * 32 + 4);
    }

    for (int t = 0; t <= 95; ++t) {
        // ---- stream wlin kt 4..7 (independent of arrive; lands during spin) ----
        short8_t wls[8][4];
        if (t >= 64) {
#pragma unroll
            for (int cf = 0; cf < 8; ++cf)
#pragma unroll
                for (int kk = 0; kk < 4; ++kk)
                    wls[cf][kk] = *(const short8_t*)&g_Wlin[(cf * 8 + 4 + kk) * 512 + l * 8];
        }

        if (t < 64) {
            // convert prefetched x(t) floats -> bf16 A-frags
#pragma unroll
            for (int kt = 0; kt < 4; ++kt) {
                short8_t vv;
                vv[0] = (short)f2bf_rn(xf[2 * kt][0]); vv[1] = (short)f2bf_rn(xf[2 * kt][1]);
                vv[2] = (short)f2bf_rn(xf[2 * kt][2]); vv[3] = (short)f2bf_rn(xf[2 * kt][3]);
                vv[4] = (short)f2bf_rn(xf[2 * kt + 1][0]); vv[5] = (short)f2bf_rn(xf[2 * kt + 1][1]);
                vv[6] = (short)f2bf_rn(xf[2 * kt + 1][2]); vv[7] = (short)f2bf_rn(xf[2 * kt + 1][3]);
                xa[kt] = vv;
            }
            if (t <= 62) {                      // prefetch x(t+1)
                const float* xp = xrow + (t + 1) * 128;
#pragma unroll
                for (int kt = 0; kt < 4; ++kt) {
                    xf[2 * kt]     = *(const float4_t*)(xp + kt * 32);
                    xf[2 * kt + 1] = *(const float4_t*)(xp + kt * 32 + 4);
                }
            }
        }

        // ---- wait for h(t-1), load A-frags ----
        if (t > 0) {
            if (tid == 0) {
                int it = 0;
                while (__hip_atomic_load(&g_arrive[rg * 96 + t - 1], __ATOMIC_ACQUIRE,
                                         __HIP_MEMORY_SCOPE_AGENT) < NB_C) {
                    if (++it > (1 << 15)) break;   // bounded: no-hang on residency failure
                    __builtin_amdgcn_s_sleep(2);
                }
                __threadfence();
            }
            __syncthreads();
            const unsigned short* hb = &g_hbuf[rg][(t - 1) & 1][wv * 8][0];
#pragma unroll
            for (int kt = 0; kt < 8; ++kt)
                ha[kt] = *(const short8_t*)(hb + kt * 512 + l * 8);
        }

        // ---- pred(t-1) = h(t-1) @ wlin^T + b (AR steps; also feeds xa) ----
        if (t >= 64) {
            float4_t pacc[8];
#pragma unroll
            for (int cf = 0; cf < 8; ++cf) {
                float b = blin_r[cf];
                pacc[cf] = (float4_t){b, b, b, b};
            }
#pragma unroll
            for (int kt = 0; kt < 8; ++kt)
#pragma unroll
                for (int cf = 0; cf < 8; ++cf) {
                    short8_t wf = (kt < 4) ? wl[cf][kt] : wls[cf][kt - 4];
                    pacc[cf] = __builtin_amdgcn_mfma_f32_16x16x32_bf16(ha[kt], wf, pacc[cf], 0, 0, 0);
                }
            int ko = t - 64;
            float* orow = out + ((size_t)(rg * 64 + wv * 16 + lg * 4) * 32 + ko) * 128 + c * 16 + l15;
#pragma unroll
            for (int cf = 0; cf < 8; ++cf)      // static-index guarded write (avoid scratch)
                if (cf == c) {
#pragma unroll
                    for (int r = 0; r < 4; ++r)
                        orow[(size_t)r * 32 * 128] = pacc[cf][r];
                }
            if (t == 95) break;
            // stage full pred -> wave-private swizzled LDS -> xa A-frags
            char* pb = (char*)&pst[wv][0];
#pragma unroll
            for (int cf = 0; cf < 8; ++cf)
#pragma unroll
                for (int r = 0; r < 4; ++r) {
                    int m = lg * 4 + r;
                    int off = (m * 256 + (cf * 16 + l15) * 2) ^ ((m & 7) << 4);
                    *(unsigned short*)(pb + off) = f2bf_rn(pacc[cf][r]);
                }
#pragma unroll
            for (int kt = 0; kt < 4; ++kt) {
                int off = (l15 * 256 + kt * 64 + lg * 16) ^ ((l15 & 7) << 4);
                xa[kt] = *(const short8_t*)(pb + off);
            }
        }

        // ---- gates GEMM: h-part first (kt 4..11), then x-part (kt 0..3) ----
        float4_t acc[4][2];
#pragma unroll
        for (int g = 0; g < 4; ++g)
#pragma unroll
            for (int s2 = 0; s2 < 2; ++s2) {
                float b = bias_r[g][s2];
                acc[g][s2] = (float4_t){b, b, b, b};
            }
#pragma unroll
        for (int ki = 0; ki < 12; ++ki) {
            int kt = (ki < 8) ? ki + 4 : ki - 8;
            short8_t a = (kt < 4) ? xa[kt] : ha[kt - 4];
#pragma unroll
            for (int g = 0; g < 4; ++g)
#pragma unroll
                for (int s2 = 0; s2 < 2; ++s2) {
                    const short8_t wf = *(const short8_t*)&gw[((g * 2 + s2) * 12 + kt) * 512 + l * 8];
                    acc[g][s2] = __builtin_amdgcn_mfma_f32_16x16x32_bf16(a, wf, acc[g][s2], 0, 0, 0);
                }
        }

        // ---- pointwise + h-frag exchange write ----
        unsigned short* hw = &g_hbuf[rg][t & 1][wv * 8 + c][0];
#pragma unroll
        for (int s2 = 0; s2 < 2; ++s2)
#pragma unroll
            for (int r = 0; r < 4; ++r) {
                float ip = acc[0][s2][r];
                float fp = acc[1][s2][r];
                float gp = acc[2][s2][r];
                float op = acc[3][s2][r];
                float cn = sigm(fp) * c_st[s2][r] + sigm(ip) * tanh_fast(gp);
                c_st[s2][r] = cn;
                float hv = sigm(op) * tanh_fast(cn);
                int m = lg * 4 + r;
                int dim = s2 * 16 + l15;
                hw[((dim >> 3) * 16 + m) * 8 + (dim & 7)] = f2bf_rn(hv);
            }
        asm volatile("s_waitcnt vmcnt(0)" ::: "memory");
        __syncthreads();
        if (tid == 0) {
            __threadfence();
            __hip_atomic_fetch_add(&g_arrive[rg * 96 + t], 1, __ATOMIC_RELEASE,
                                   __HIP_MEMORY_SCOPE_AGENT);
        }
    }
}

extern "C" void kernel_launch(void* const* d_in, const int* in_sizes, int n_in,
                              void* d_out, int out_size, void* d_ws, size_t ws_size,
                              hipStream_t stream) {
    const float* inp   = (const float*)d_in[0];
    const float* w_ih  = (const float*)d_in[1];
    const float* w_hh  = (const float*)d_in[2];
    const float* b_ih  = (const float*)d_in[3];
    const float* b_hh  = (const float*)d_in[4];
    const float* w_lin = (const float*)d_in[5];
    const float* b_lin = (const float*)d_in[6];
    (void)in_sizes; (void)n_in; (void)d_ws; (void)ws_size; (void)out_size;

    prep_kernel<<<128, 256, 0, stream>>>(w_ih, w_hh, b_ih, b_hh, w_lin, b_lin);
    lstm_persist<<<256, 256, 0, stream>>>(inp, (float*)d_out);
}

// Round 3
// 606.172 us; speedup vs baseline: 4.8874x; 3.8920x over previous
//
#include <hip/hip_runtime.h>
#include <cstdint>
#include <cstddef>

typedef short short8_t __attribute__((ext_vector_type(8)));
typedef float float4_t __attribute__((ext_vector_type(4)));

#define NRG 32   // row-groups (64 batch rows each); 8 col-blocks per rg

// Fragment-packed weights (rebuilt from d_in every call).
// g_W frag f = ((g*4+w)*4+s)*12 + kt (enc: k 0..127 = Wih, 128..383 = Whh)
__device__ __align__(16) unsigned short g_W[1024 * 384];
// g_Weff frag f = ((g*4+w)*4+s)*8 + kt2 ; Weff = Whh + Wih @ wlin  (AR recurrence)
__device__ __align__(16) unsigned short g_Weff[1024 * 256];
__device__ __align__(16) unsigned short g_Wlin[128 * 256];
__device__ float g_bias[1024];   // b_ih + b_hh
__device__ float g_beff[1024];   // bias + Wih @ b_lin
__device__ float g_blin[128];
// h exchange: [rg][parity][row 0..63][dim 0..255] bf16, accessed ONLY via sc0/sc1 ops
__device__ __align__(16) unsigned short g_hx[NRG][2][64][256];
__device__ int g_flag[NRG][4][8];   // [rg][wave][col-block] = last step+1 written

__device__ __forceinline__ unsigned short f2bf_rn(float f) {
    union { float f; unsigned int u; } v; v.f = f;
    unsigned int u = v.u;
    return (unsigned short)((u + 0x7FFFu + ((u >> 16) & 1u)) >> 16);
}
__device__ __forceinline__ float sigm(float x) { return 1.0f / (1.0f + __expf(-x)); }
__device__ __forceinline__ float tanh_fast(float x) { return 2.0f / (1.0f + __expf(-2.0f * x)) - 1.0f; }

__global__ void prep_kernel(const float* __restrict__ w_ih, const float* __restrict__ w_hh,
                            const float* __restrict__ b_ih, const float* __restrict__ b_hh,
                            const float* __restrict__ w_lin, const float* __restrict__ b_lin) {
    int idx = blockIdx.x * blockDim.x + threadIdx.x;
    int stride = gridDim.x * blockDim.x;
    for (int i = idx; i < 49152; i += stride) {   // 768 frags * 64 lanes
        int f = i >> 6, l = i & 63;
        int kt = f % 12, rest = f / 12;
        int s = rest & 3, wvv = (rest >> 2) & 3, g = rest >> 4;
        int n = g * 256 + wvv * 64 + s * 16 + (l & 15);
        int k0 = kt * 32 + (l >> 4) * 8;
        unsigned short* dst = g_W + f * 512 + l * 8;
#pragma unroll
        for (int j = 0; j < 8; ++j) {
            int k = k0 + j;
            float v = (k < 128) ? w_ih[n * 128 + k] : w_hh[n * 256 + (k - 128)];
            dst[j] = f2bf_rn(v);
        }
    }
    for (int i = idx; i < 4096; i += stride) {    // wlin: 64 frags * 64 lanes
        int f = i >> 6, l = i & 63;
        int kt = f & 7, wss = f >> 3;
        int s = wss & 1, wvv = wss >> 1;
        int n = wvv * 32 + s * 16 + (l & 15);
        int k0 = kt * 32 + (l >> 4) * 8;
        unsigned short* dst = g_Wlin + f * 512 + l * 8;
#pragma unroll
        for (int j = 0; j < 8; ++j)
            dst[j] = f2bf_rn(w_lin[n * 256 + k0 + j]);
    }
    for (int i = idx; i < 1024; i += stride) g_bias[i] = b_ih[i] + b_hh[i];
    for (int i = idx; i < 128; i += stride) g_blin[i] = b_lin[i];
    for (int i = idx; i < NRG * 32; i += stride) ((int*)g_flag)[i] = 0;
}

// Weff[n][k] = Whh[n][k] + sum_p Wih[n][p]*wlin[p][k]; beff[n] = bias[n]+sum Wih[n][p]*blin[p]
__global__ void prep2_kernel(const float* __restrict__ w_ih, const float* __restrict__ w_hh,
                             const float* __restrict__ w_lin, const float* __restrict__ b_ih,
                             const float* __restrict__ b_hh, const float* __restrict__ b_lin) {
    int i = blockIdx.x * 256 + threadIdx.x;       // grid 1024*256 = 262144
    {
        int e = i & 511, f = i >> 9;
        int l = e >> 3, j = e & 7;
        int kt2 = f & 7, rest = f >> 3;
        int s = rest & 3, w = (rest >> 2) & 3, g = rest >> 4;
        int n = g * 256 + w * 64 + s * 16 + (l & 15);
        int k = kt2 * 32 + (l >> 4) * 8 + j;
        float acc = w_hh[n * 256 + k];
#pragma unroll 4
        for (int p = 0; p < 128; ++p)
            acc += w_ih[n * 128 + p] * w_lin[p * 256 + k];
        g_Weff[f * 512 + e] = f2bf_rn(acc);
    }
    if (i < 1024) {
        float acc = b_ih[i] + b_hh[i];
        for (int p = 0; p < 128; ++p)
            acc += w_ih[i * 128 + p] * b_lin[p];
        g_beff[i] = acc;
    }
}

// 256 blocks = 32 rg x 8 c. Block (rg,c): 64 rows, h/gate dims [c*32,c*32+32).
// Barrier-free steady state: per-wave flag handshake through L3 (sc0 sc1 ops).
__global__ void __launch_bounds__(256, 1) lstm_persist(const float* __restrict__ inp,
                                                       float* __restrict__ out) {
    __shared__ __align__(16) unsigned short gw[96 * 512];     // 96 KiB weights (enc; AR reuses 64)
    __shared__ __align__(16) unsigned short wl_sh[8 * 512];   // 8 KiB wlin slice (cols c*16..)
    __shared__ __align__(16) unsigned short tb[4][512];       // 1 KiB/wave transpose buf

    const int tid = threadIdx.x;
    const int wv = tid >> 6, l = tid & 63, l15 = l & 15, lg = l >> 4;
    const int c = blockIdx.x >> 5, rg = blockIdx.x & 31;

    for (int i = tid; i < 96 * 64; i += 256) {
        int lf = i >> 6, ch = i & 63;
        int kt = lf % 12, gs = lf / 12;
        int s2 = gs & 1, g = gs >> 1;
        int gf = ((g * 4 + (c >> 1)) * 4 + 2 * (c & 1) + s2) * 12 + kt;
        *(uint4*)&gw[lf * 512 + ch * 8] = *(const uint4*)&g_W[gf * 512 + ch * 8];
    }
    for (int i = tid; i < 8 * 64; i += 256) {
        int lf = i >> 6, ch = i & 63;
        *(uint4*)&wl_sh[lf * 512 + ch * 8] = *(const uint4*)&g_Wlin[(c * 8 + lf) * 512 + ch * 8];
    }
    float biasr[4][2], beffr[4][2];
#pragma unroll
    for (int g = 0; g < 4; ++g)
#pragma unroll
        for (int s2 = 0; s2 < 2; ++s2) {
            biasr[g][s2] = g_bias[g * 256 + c * 32 + s2 * 16 + l15];
            beffr[g][s2] = g_beff[g * 256 + c * 32 + s2 * 16 + l15];
        }
    const float blin_r = g_blin[c * 16 + l15];
    __syncthreads();

    short8_t ha[8], xa[4];
    short8_t zz = {0, 0, 0, 0, 0, 0, 0, 0};
#pragma unroll
    for (int i = 0; i < 8; ++i) ha[i] = zz;
#pragma unroll
    for (int i = 0; i < 4; ++i) xa[i] = zz;
    float c_st[2][4];
#pragma unroll
    for (int s2 = 0; s2 < 2; ++s2)
#pragma unroll
        for (int r = 0; r < 4; ++r) c_st[s2][r] = 0.0f;

    const float* xrow = inp + (size_t)(rg * 64 + wv * 16 + l15) * 8192 + lg * 8;
    float4_t xf[8];
#pragma unroll
    for (int kt = 0; kt < 4; ++kt) {
        xf[2 * kt]     = *(const float4_t*)(xrow + kt * 32);
        xf[2 * kt + 1] = *(const float4_t*)(xrow + kt * 32 + 4);
    }

    for (int t = 0; t <= 95; ++t) {
        if (t == 64) {   // one-time: overwrite gw slots 0..63 with Weff slice
            __syncthreads();
            for (int i = tid; i < 64 * 64; i += 256) {
                int lf = i >> 6, ch = i & 63;
                int kt2 = lf & 7, gs = lf >> 3;
                int s2 = gs & 1, g = gs >> 1;
                int gf = ((g * 4 + (c >> 1)) * 4 + 2 * (c & 1) + s2) * 8 + kt2;
                *(uint4*)&gw[lf * 512 + ch * 8] = *(const uint4*)&g_Weff[gf * 512 + ch * 8];
            }
            __syncthreads();
        }

        float4_t acc[4][2];
        if (t < 95) {
#pragma unroll
            for (int g = 0; g < 4; ++g)
#pragma unroll
                for (int s2 = 0; s2 < 2; ++s2) {
                    float b = (t < 64) ? biasr[g][s2] : beffr[g][s2];
                    acc[g][s2] = (float4_t){b, b, b, b};
                }
        }

        if (t < 64) {
            // x(t): convert prefetched floats, issue prefetch x(t+1), x-part MFMAs (pre-poll)
#pragma unroll
            for (int kt = 0; kt < 4; ++kt) {
                short8_t vv;
                vv[0] = (short)f2bf_rn(xf[2 * kt][0]); vv[1] = (short)f2bf_rn(xf[2 * kt][1]);
                vv[2] = (short)f2bf_rn(xf[2 * kt][2]); vv[3] = (short)f2bf_rn(xf[2 * kt][3]);
                vv[4] = (short)f2bf_rn(xf[2 * kt + 1][0]); vv[5] = (short)f2bf_rn(xf[2 * kt + 1][1]);
                vv[6] = (short)f2bf_rn(xf[2 * kt + 1][2]); vv[7] = (short)f2bf_rn(xf[2 * kt + 1][3]);
                xa[kt] = vv;
            }
            if (t <= 62) {
                const float* xp = xrow + (t + 1) * 128;
#pragma unroll
                for (int kt = 0; kt < 4; ++kt) {
                    xf[2 * kt]     = *(const float4_t*)(xp + kt * 32);
                    xf[2 * kt + 1] = *(const float4_t*)(xp + kt * 32 + 4);
                }
            }
#pragma unroll
            for (int kt = 0; kt < 4; ++kt)
#pragma unroll
                for (int g = 0; g < 4; ++g)
#pragma unroll
                    for (int s2 = 0; s2 < 2; ++s2) {
                        const short8_t wf = *(const short8_t*)&gw[((g * 2 + s2) * 12 + kt) * 512 + l * 8];
                        acc[g][s2] = __builtin_amdgcn_mfma_f32_16x16x32_bf16(xa[kt], wf, acc[g][s2], 0, 0, 0);
                    }
        }

        if (t > 0) {
            // ---- poll peer flags (relaxed, L2-bypass), then load h(t-1) A-frags ----
            __builtin_amdgcn_sched_barrier(0);
            const int* fp = &g_flag[rg][wv][l & 7];
            int fv, guard = 0;
            do {
                asm volatile("global_load_dword %0, %1, off sc0 sc1\n\ts_waitcnt vmcnt(0)"
                             : "=v"(fv) : "v"(fp) : "memory");
            } while (!__all(fv >= t) && ++guard < (1 << 15));
            __builtin_amdgcn_sched_barrier(0);
            const char* hb = (const char*)&g_hx[rg][(t - 1) & 1][wv * 16 + l15][lg * 8];
#pragma unroll
            for (int kt = 0; kt < 8; ++kt)
                asm volatile("global_load_dwordx4 %0, %1, off sc0 sc1"
                             : "=v"(ha[kt]) : "v"(hb + kt * 64) : "memory");
            asm volatile("s_waitcnt vmcnt(0)" ::: "memory");
            __builtin_amdgcn_sched_barrier(0);
        }

        if (t < 95) {
            // ---- h-part gates MFMA ----
            if (t > 0) {
                if (t < 64) {
#pragma unroll
                    for (int kt = 4; kt < 12; ++kt)
#pragma unroll
                        for (int g = 0; g < 4; ++g)
#pragma unroll
                            for (int s2 = 0; s2 < 2; ++s2) {
                                const short8_t wf = *(const short8_t*)&gw[((g * 2 + s2) * 12 + kt) * 512 + l * 8];
                                acc[g][s2] = __builtin_amdgcn_mfma_f32_16x16x32_bf16(ha[kt - 4], wf, acc[g][s2], 0, 0, 0);
                            }
                } else {
#pragma unroll
                    for (int kt = 0; kt < 8; ++kt)
#pragma unroll
                        for (int g = 0; g < 4; ++g)
#pragma unroll
                            for (int s2 = 0; s2 < 2; ++s2) {
                                const short8_t wf = *(const short8_t*)&gw[((g * 2 + s2) * 8 + kt) * 512 + l * 8];
                                acc[g][s2] = __builtin_amdgcn_mfma_f32_16x16x32_bf16(ha[kt], wf, acc[g][s2], 0, 0, 0);
                            }
                }
            }
            // ---- pointwise -> swizzled in-wave transpose -> sc1 store -> flag ----
            char* tbw = (char*)&tb[wv][0];
#pragma unroll
            for (int s2 = 0; s2 < 2; ++s2)
#pragma unroll
                for (int r = 0; r < 4; ++r) {
                    float ip = acc[0][s2][r], fpv = acc[1][s2][r];
                    float gp = acc[2][s2][r], op = acc[3][s2][r];
                    float cn = sigm(fpv) * c_st[s2][r] + sigm(ip) * tanh_fast(gp);
                    c_st[s2][r] = cn;
                    float hv = sigm(op) * tanh_fast(cn);
                    int m = lg * 4 + r;
                    int boff = (m * 64 + (s2 * 16 + l15) * 2) ^ (lg << 4);
                    *(unsigned short*)(tbw + boff) = f2bf_rn(hv);
                }
            int roff = (l15 * 64 + (lg << 4)) ^ ((l15 >> 2) << 4);
            short8_t hv8 = *(const short8_t*)(tbw + roff);
            char* dst = (char*)&g_hx[rg][t & 1][wv * 16 + l15][c * 32 + lg * 8];
            asm volatile("global_store_dwordx4 %0, %1, off sc0 sc1" :: "v"(dst), "v"(hv8) : "memory");
            asm volatile("s_waitcnt vmcnt(0)" ::: "memory");
            if (l == 0) {
                int* fw = &g_flag[rg][wv][c];
                int nv = t + 1;
                asm volatile("global_store_dword %0, %1, off sc0 sc1" :: "v"(fw), "v"(nv) : "memory");
            }
        }

        // ---- pred(t-1) for output (after flag: off the critical path) ----
        if (t >= 64) {
            float4_t pacc = {blin_r, blin_r, blin_r, blin_r};
#pragma unroll
            for (int kt = 0; kt < 8; ++kt) {
                const short8_t wf = *(const short8_t*)&wl_sh[kt * 512 + l * 8];
                pacc = __builtin_amdgcn_mfma_f32_16x16x32_bf16(ha[kt], wf, pacc, 0, 0, 0);
            }
            int ko = t - 64;
            float* orow = out + ((size_t)(rg * 64 + wv * 16 + lg * 4) * 32 + ko) * 128 + c * 16 + l15;
#pragma unroll
            for (int r = 0; r < 4; ++r)
                orow[(size_t)r * 32 * 128] = pacc[r];
        }
    }
}

extern "C" void kernel_launch(void* const* d_in, const int* in_sizes, int n_in,
                              void* d_out, int out_size, void* d_ws, size_t ws_size,
                              hipStream_t stream) {
    const float* inp   = (const float*)d_in[0];
    const float* w_ih  = (const float*)d_in[1];
    const float* w_hh  = (const float*)d_in[2];
    const float* b_ih  = (const float*)d_in[3];
    const float* b_hh  = (const float*)d_in[4];
    const float* w_lin = (const float*)d_in[5];
    const float* b_lin = (const float*)d_in[6];
    (void)in_sizes; (void)n_in; (void)d_ws; (void)ws_size; (void)out_size;

    prep_kernel<<<128, 256, 0, stream>>>(w_ih, w_hh, b_ih, b_hh, w_lin, b_lin);
    prep2_kernel<<<1024, 256, 0, stream>>>(w_ih, w_hh, w_lin, b_ih, b_hh, b_lin);
    lstm_persist<<<256, 256, 0, stream>>>(inp, (float*)d_out);
}